// Round 2
// baseline (201.617 us; speedup 1.0000x reference)
//
#include <hip/hip_runtime.h>

#define T_DIM 32
#define N_DIM 512
#define E_DIM 64
#define F_DIM 64
#define HD    64

static_assert(E_DIM == 64 && HD == 64 && F_DIM == 64, "wave-mapped dims");

__device__ __forceinline__ float wave_sum(float v) {
    #pragma unroll
    for (int off = 32; off > 0; off >>= 1) v += __shfl_xor(v, off, 64);
    return v;
}
__device__ __forceinline__ float wave_max(float v) {
    #pragma unroll
    for (int off = 32; off > 0; off >>= 1) v = fmaxf(v, __shfl_xor(v, off, 64));
    return v;
}

// K1: h = x @ W  [T*N, 64]; s_hyp/s_ind = leaky_relu(h @ a, 0.2)
__global__ __launch_bounds__(256) void k1_h_s(
    const float* __restrict__ x, const float* __restrict__ W,
    const float* __restrict__ a_hyp, const float* __restrict__ a_ind,
    float* __restrict__ h, float* __restrict__ s_hyp, float* __restrict__ s_ind)
{
    const int wave = threadIdx.x >> 6;
    const int lane = threadIdx.x & 63;
    const int row  = blockIdx.x * 4 + wave;          // t*N + n
    const float xv = x[row * F_DIM + lane];
    float acc = 0.f;
    #pragma unroll
    for (int f = 0; f < F_DIM; ++f)
        acc = fmaf(__shfl(xv, f, 64), W[f * HD + lane], acc);
    h[row * HD + lane] = acc;
    const float sh = wave_sum(acc * a_hyp[lane]);
    const float si = wave_sum(acc * a_ind[lane]);
    if (lane == 0) {
        s_hyp[row] = sh > 0.f ? sh : 0.2f * sh;
        s_ind[row] = si > 0.f ? si : 0.2f * si;
    }
}

// K23: fused. Blocks [0, T*E/4): per-(t,e) masked softmax stats over nodes.
//      Blocks [T*E/4, ...): per-(t,i) industry attention row.
#define K2_BLOCKS (T_DIM * E_DIM / 4)
__global__ __launch_bounds__(256) void k23_stats_industry(
    const int* __restrict__ Hm, const int* __restrict__ adj,
    const float* __restrict__ s_hyp, const float* __restrict__ s_ind,
    const float* __restrict__ h,
    float* __restrict__ m_e, float* __restrict__ d_e,
    float* __restrict__ industry)
{
    const int wave = threadIdx.x >> 6;
    const int lane = threadIdx.x & 63;

    if (blockIdx.x < K2_BLOCKS) {
        // ---- edge stats ----
        const int idx = blockIdx.x * 4 + wave;       // t*E + e
        const int t = idx >> 6;
        const int e = idx & 63;
        int   mem[N_DIM / 64];
        float sv [N_DIM / 64];
        float mx = -3.0e38f;
        #pragma unroll
        for (int c = 0; c < N_DIM / 64; ++c) {
            const int n = c * 64 + lane;
            mem[c] = Hm[n * E_DIM + e];
            sv [c] = s_hyp[t * N_DIM + n];
            if (mem[c]) mx = fmaxf(mx, sv[c]);
        }
        mx = wave_max(mx);
        float sum = 0.f;
        #pragma unroll
        for (int c = 0; c < N_DIM / 64; ++c)
            if (mem[c]) sum += expf(sv[c] - mx);
        sum = wave_sum(sum);
        if (lane == 0) { m_e[idx] = mx; d_e[idx] = sum; }
    } else {
        // ---- industry attention ----
        const int idx = (blockIdx.x - K2_BLOCKS) * 4 + wave;  // t*N + i
        const int t = idx >> 9;
        const int i = idx & (N_DIM - 1);
        const int*   arow = adj + i * N_DIM;
        const float* srow = s_ind + t * N_DIM;
        int   mem[N_DIM / 64];
        float sv [N_DIM / 64];
        float mx = -3.0e38f;
        #pragma unroll
        for (int c = 0; c < N_DIM / 64; ++c) {
            const int j = c * 64 + lane;
            mem[c] = arow[j];
            sv [c] = srow[j];
            if (mem[c]) mx = fmaxf(mx, sv[c]);
        }
        mx = wave_max(mx);
        const float* hbase = h + t * N_DIM * HD;
        float acc = 0.f, sum = 0.f;
        #pragma unroll
        for (int c = 0; c < N_DIM / 64; ++c) {
            const float ev = mem[c] ? expf(sv[c] - mx) : 0.f;
            sum += ev;
            unsigned long long mk = __ballot(mem[c] != 0);
            while (mk) {
                const int b = __ffsll((long long)mk) - 1;
                mk &= mk - 1;
                const float w = __shfl(ev, b, 64);
                acc = fmaf(w, hbase[(c * 64 + b) * HD + lane], acc);
            }
        }
        sum = wave_sum(sum);
        industry[idx * HD + lane] = acc / sum;
    }
}

// K4: per (t,n): y8 = edgeconv over member hyperedges; y9 = edgeconv over
// {industry, y8}. Wc1 column held in 64 VGPRs per lane; broadcasts via readlane.
__global__ __launch_bounds__(256) void k4_final(
    const int* __restrict__ Hm, const float* __restrict__ s_hyp,
    const float* __restrict__ m_e, const float* __restrict__ d_e,
    const float* __restrict__ h, const float* __restrict__ industry,
    const float* __restrict__ Wc1, const float* __restrict__ bc1,
    const float* __restrict__ wc2, const float* __restrict__ bc2,
    float* __restrict__ out)
{
    const int wave = threadIdx.x >> 6;
    const int lane = threadIdx.x & 63;
    const int idx  = blockIdx.x * 4 + wave;          // t*N + n
    const int t = idx >> 9;
    const int n = idx & (N_DIM - 1);

    float wreg[HD];                                  // Wc1[:, lane]
    #pragma unroll
    for (int d = 0; d < HD; ++d) wreg[d] = Wc1[d * HD + lane];
    const float bc1v = bc1[lane];
    const float wc2v = wc2[lane];
    const float bc2v = bc2[0];

    const float hv = h[idx * HD + lane];
    const float sh = s_hyp[idx];

    // member edges of node n: lane plays role of e
    const int memv = Hm[n * E_DIM + lane];
    float alpha_e = 0.f;
    if (memv)
        alpha_e = expf(sh - m_e[t * E_DIM + lane]) * __frcp_rn(d_e[t * E_DIM + lane]);
    unsigned long long mk = __ballot(memv != 0);

    float zmax = -3.0e38f, zsum = 0.f, acc = 0.f;
    while (mk) {
        const int e = __ffsll((long long)mk) - 1;
        mk &= mk - 1;
        const float a = __shfl(alpha_e, e, 64);
        float f = a * hv;
        f = f > 0.f ? f : expm1f(f);                 // elu
        float u = 0.f;
        #pragma unroll
        for (int d = 0; d < HD; ++d)
            u = fmaf(__shfl(f, d, 64), wreg[d], u);
        const float z = wave_sum(fmaxf(u + bc1v, 0.f) * wc2v) + bc2v;
        if (z > zmax) {                              // online softmax
            const float sc = expf(zmax - z);
            acc *= sc; zsum *= sc; zmax = z;
        }
        const float w = expf(z - zmax);
        zsum += w;
        acc = fmaf(w, f, acc);
    }
    const float y8 = acc / zsum;

    // final pair edgeconv over {industry, y8}
    const float indv = industry[idx * HD + lane];
    float u0 = 0.f, u1 = 0.f;
    #pragma unroll
    for (int d = 0; d < HD; ++d) {
        u0 = fmaf(__shfl(indv, d, 64), wreg[d], u0);
        u1 = fmaf(__shfl(y8,   d, 64), wreg[d], u1);
    }
    const float z0 = wave_sum(fmaxf(u0 + bc1v, 0.f) * wc2v) + bc2v;
    const float z1 = wave_sum(fmaxf(u1 + bc1v, 0.f) * wc2v) + bc2v;
    const float zm = fmaxf(z0, z1);
    const float w0 = expf(z0 - zm), w1 = expf(z1 - zm);
    out[idx * HD + lane] = fmaf(w0, indv, w1 * y8) / (w0 + w1);
}

extern "C" void kernel_launch(void* const* d_in, const int* in_sizes, int n_in,
                              void* d_out, int out_size, void* d_ws, size_t ws_size,
                              hipStream_t stream) {
    const float* x     = (const float*)d_in[0];
    const int*   Hm    = (const int*)  d_in[1];
    const int*   adj   = (const int*)  d_in[2];
    // d_in[3] = nhid (unused scalar)
    const float* W     = (const float*)d_in[4];
    const float* a_hyp = (const float*)d_in[5];
    const float* a_ind = (const float*)d_in[6];
    const float* Wc1   = (const float*)d_in[7];
    const float* bc1   = (const float*)d_in[8];
    const float* wc2   = (const float*)d_in[9];
    const float* bc2   = (const float*)d_in[10];
    float* out = (float*)d_out;

    float* ws       = (float*)d_ws;
    float* h        = ws;                                 // T*N*HD
    float* s_hyp    = h + (size_t)T_DIM * N_DIM * HD;     // T*N
    float* s_ind    = s_hyp + T_DIM * N_DIM;              // T*N
    float* m_e      = s_ind + T_DIM * N_DIM;              // T*E
    float* d_e      = m_e + T_DIM * E_DIM;                // T*E
    float* industry = d_e + T_DIM * E_DIM;                // T*N*HD

    k1_h_s<<<T_DIM * N_DIM / 4, 256, 0, stream>>>(x, W, a_hyp, a_ind, h, s_hyp, s_ind);
    k23_stats_industry<<<K2_BLOCKS + T_DIM * N_DIM / 4, 256, 0, stream>>>(
        Hm, adj, s_hyp, s_ind, h, m_e, d_e, industry);
    k4_final<<<T_DIM * N_DIM / 4, 256, 0, stream>>>(Hm, s_hyp, m_e, d_e, h, industry,
                                                    Wc1, bc1, wc2, bc2, out);
}

// Round 3
// 141.485 us; speedup vs baseline: 1.4250x; 1.4250x over previous
//
#include <hip/hip_runtime.h>

#define T_DIM 32
#define N_DIM 512
#define E_DIM 64
#define F_DIM 64
#define HD    64

static_assert(E_DIM == 64 && HD == 64 && F_DIM == 64, "wave-mapped dims");

__device__ __forceinline__ float wave_sum(float v) {
    #pragma unroll
    for (int off = 32; off > 0; off >>= 1) v += __shfl_xor(v, off, 64);
    return v;
}
__device__ __forceinline__ float wave_max(float v) {
    #pragma unroll
    for (int off = 32; off > 0; off >>= 1) v = fmaxf(v, __shfl_xor(v, off, 64));
    return v;
}

// ---------------------------------------------------------------------------
// K1: h = x @ W  [T*N, 64]; s_hyp/s_ind = leaky_relu(h @ a, 0.2)
// Layout: lane = output column j. W[:,j] in 64 VGPRs. x row broadcast from LDS
// as float4 (independent ds_read_b128 broadcasts -> ILP, no shfl chain).
// ---------------------------------------------------------------------------
#define K1_R 16  // rows per block (256 threads load exactly K1_R*64 floats as float4)
__global__ __launch_bounds__(256) void k1_h_s(
    const float* __restrict__ x, const float* __restrict__ W,
    const float* __restrict__ a_hyp, const float* __restrict__ a_ind,
    float* __restrict__ h, float* __restrict__ s_hyp, float* __restrict__ s_ind)
{
    __shared__ float xl[K1_R * F_DIM];
    const int wave = threadIdx.x >> 6;
    const int lane = threadIdx.x & 63;
    const int row0 = blockIdx.x * K1_R;

    ((float4*)xl)[threadIdx.x] = ((const float4*)(x + (size_t)row0 * F_DIM))[threadIdx.x];

    float wcol[F_DIM];                                // W[:, lane]
    #pragma unroll
    for (int f = 0; f < F_DIM; ++f) wcol[f] = W[f * HD + lane];
    const float ah = a_hyp[lane], ai = a_ind[lane];
    __syncthreads();

    #pragma unroll
    for (int r = wave; r < K1_R; r += 4) {
        float a0 = 0.f, a1 = 0.f, a2 = 0.f, a3 = 0.f;
        #pragma unroll
        for (int f = 0; f < F_DIM; f += 4) {
            const float4 xv = *(const float4*)&xl[r * F_DIM + f];  // broadcast
            a0 = fmaf(xv.x, wcol[f + 0], a0);
            a1 = fmaf(xv.y, wcol[f + 1], a1);
            a2 = fmaf(xv.z, wcol[f + 2], a2);
            a3 = fmaf(xv.w, wcol[f + 3], a3);
        }
        const float acc = (a0 + a1) + (a2 + a3);
        h[(size_t)(row0 + r) * HD + lane] = acc;
        const float sh = wave_sum(acc * ah);
        const float si = wave_sum(acc * ai);
        if (lane == 0) {
            s_hyp[row0 + r] = sh > 0.f ? sh : 0.2f * sh;
            s_ind[row0 + r] = si > 0.f ? si : 0.2f * si;
        }
    }
}

// ---------------------------------------------------------------------------
// K23 fused: blocks [0, K2_BLOCKS) do per-(t,e) masked softmax stats;
//            the rest do per-(t,i) industry attention rows.
// ---------------------------------------------------------------------------
#define K2_BLOCKS (T_DIM * E_DIM / 4)
__global__ __launch_bounds__(256) void k23_stats_industry(
    const int* __restrict__ Hm, const int* __restrict__ adj,
    const float* __restrict__ s_hyp, const float* __restrict__ s_ind,
    const float* __restrict__ h,
    float* __restrict__ m_e, float* __restrict__ d_e,
    float* __restrict__ industry)
{
    const int wave = threadIdx.x >> 6;
    const int lane = threadIdx.x & 63;

    if (blockIdx.x < K2_BLOCKS) {
        const int idx = blockIdx.x * 4 + wave;       // t*E + e
        const int t = idx >> 6;
        const int e = idx & 63;
        int   mem[N_DIM / 64];
        float sv [N_DIM / 64];
        float mx = -3.0e38f;
        #pragma unroll
        for (int c = 0; c < N_DIM / 64; ++c) {
            const int n = c * 64 + lane;
            mem[c] = Hm[n * E_DIM + e];
            sv [c] = s_hyp[t * N_DIM + n];
            if (mem[c]) mx = fmaxf(mx, sv[c]);
        }
        mx = wave_max(mx);
        float sum = 0.f;
        #pragma unroll
        for (int c = 0; c < N_DIM / 64; ++c)
            if (mem[c]) sum += expf(sv[c] - mx);
        sum = wave_sum(sum);
        if (lane == 0) { m_e[idx] = mx; d_e[idx] = sum; }
    } else {
        const int idx = (blockIdx.x - K2_BLOCKS) * 4 + wave;  // t*N + i
        const int t = idx >> 9;
        const int i = idx & (N_DIM - 1);
        const int*   arow = adj + i * N_DIM;
        const float* srow = s_ind + t * N_DIM;
        int   mem[N_DIM / 64];
        float sv [N_DIM / 64];
        float mx = -3.0e38f;
        #pragma unroll
        for (int c = 0; c < N_DIM / 64; ++c) {
            const int j = c * 64 + lane;
            mem[c] = arow[j];
            sv [c] = srow[j];
            if (mem[c]) mx = fmaxf(mx, sv[c]);
        }
        mx = wave_max(mx);
        const float* hbase = h + (size_t)t * N_DIM * HD;
        float ac0 = 0.f, ac1 = 0.f, ac2 = 0.f, ac3 = 0.f, sum = 0.f;
        #pragma unroll
        for (int c = 0; c < N_DIM / 64; ++c) {
            const float ev = mem[c] ? expf(sv[c] - mx) : 0.f;
            sum += ev;
            unsigned long long mk = __ballot(mem[c] != 0);
            const int base = c * 64;
            while (mk) {
                // peel up to 4 neighbors -> 4 independent loads in flight
                const int b0 = __ffsll((long long)mk) - 1; mk &= mk - 1;
                const bool h1 = mk != 0;
                int b1 = 0; if (h1) { b1 = __ffsll((long long)mk) - 1; mk &= mk - 1; }
                const bool h2 = mk != 0;
                int b2 = 0; if (h2) { b2 = __ffsll((long long)mk) - 1; mk &= mk - 1; }
                const bool h3 = mk != 0;
                int b3 = 0; if (h3) { b3 = __ffsll((long long)mk) - 1; mk &= mk - 1; }
                const float v0 = hbase[(size_t)(base + b0) * HD + lane];
                const float v1 = hbase[(size_t)(base + b1) * HD + lane];
                const float v2 = hbase[(size_t)(base + b2) * HD + lane];
                const float v3 = hbase[(size_t)(base + b3) * HD + lane];
                const float w0 = __shfl(ev, b0, 64);
                const float w1 = h1 ? __shfl(ev, b1, 64) : 0.f;
                const float w2 = h2 ? __shfl(ev, b2, 64) : 0.f;
                const float w3 = h3 ? __shfl(ev, b3, 64) : 0.f;
                ac0 = fmaf(w0, v0, ac0);
                ac1 = fmaf(w1, v1, ac1);
                ac2 = fmaf(w2, v2, ac2);
                ac3 = fmaf(w3, v3, ac3);
            }
        }
        sum = wave_sum(sum);
        industry[(size_t)idx * HD + lane] = ((ac0 + ac1) + (ac2 + ac3)) / sum;
    }
}

// ---------------------------------------------------------------------------
// K4: per (t,n): y8 = edgeconv over member hyperedges; y9 = edgeconv over
// {industry, y8}. Wc1[:,lane] in VGPRs; feature vectors staged in LDS and
// broadcast-read as float4 (independent ds_read_b128 -> ILP, no shfl chain).
// ---------------------------------------------------------------------------
__global__ __launch_bounds__(256) void k4_final(
    const int* __restrict__ Hm, const float* __restrict__ s_hyp,
    const float* __restrict__ m_e, const float* __restrict__ d_e,
    const float* __restrict__ h, const float* __restrict__ industry,
    const float* __restrict__ Wc1, const float* __restrict__ bc1,
    const float* __restrict__ wc2, const float* __restrict__ bc2,
    float* __restrict__ out)
{
    __shared__ float fl[4 * 2 * HD];                 // per-wave 2x64 staging
    const int wave = threadIdx.x >> 6;
    const int lane = threadIdx.x & 63;
    const int idx  = blockIdx.x * 4 + wave;          // t*N + n
    const int t = idx >> 9;
    const int n = idx & (N_DIM - 1);
    float* fw = fl + wave * 2 * HD;                  // slot 0: f / indv, slot 1: y8

    float wreg[HD];                                  // Wc1[:, lane]
    #pragma unroll
    for (int d = 0; d < HD; ++d) wreg[d] = Wc1[d * HD + lane];
    const float bc1v = bc1[lane];
    const float wc2v = wc2[lane];
    const float bc2v = bc2[0];

    const float hv = h[(size_t)idx * HD + lane];
    const float sh = s_hyp[idx];

    const int memv = Hm[n * E_DIM + lane];           // lane = e
    float alpha_e = 0.f;
    if (memv)
        alpha_e = expf(sh - m_e[t * E_DIM + lane]) * __frcp_rn(d_e[t * E_DIM + lane]);
    unsigned long long mk = __ballot(memv != 0);

    float zmax = -3.0e38f, zsum = 0.f, acc = 0.f;
    while (mk) {
        const int e = __ffsll((long long)mk) - 1;
        mk &= mk - 1;
        const float a = __shfl(alpha_e, e, 64);
        float f = a * hv;
        f = f > 0.f ? f : expm1f(f);                 // elu
        fw[lane] = f;                                // stage for broadcast
        float u0 = 0.f, u1 = 0.f, u2 = 0.f, u3 = 0.f;
        #pragma unroll
        for (int d = 0; d < HD; d += 4) {
            const float4 fv = *(const float4*)&fw[d];   // broadcast b128
            u0 = fmaf(fv.x, wreg[d + 0], u0);
            u1 = fmaf(fv.y, wreg[d + 1], u1);
            u2 = fmaf(fv.z, wreg[d + 2], u2);
            u3 = fmaf(fv.w, wreg[d + 3], u3);
        }
        const float u = (u0 + u1) + (u2 + u3);
        const float z = wave_sum(fmaxf(u + bc1v, 0.f) * wc2v) + bc2v;
        if (z > zmax) {                              // online softmax (uniform branch)
            const float sc = expf(zmax - z);
            acc *= sc; zsum *= sc; zmax = z;
        }
        const float w = expf(z - zmax);
        zsum += w;
        acc = fmaf(w, f, acc);
    }
    const float y8 = acc / zsum;

    // final pair edgeconv over {industry, y8}
    const float indv = industry[(size_t)idx * HD + lane];
    fw[lane]      = indv;
    fw[HD + lane] = y8;
    float p0 = 0.f, p1 = 0.f, q0 = 0.f, q1 = 0.f;
    #pragma unroll
    for (int d = 0; d < HD; d += 4) {
        const float4 iv = *(const float4*)&fw[d];
        const float4 yv = *(const float4*)&fw[HD + d];
        p0 = fmaf(iv.x, wreg[d + 0], p0);
        p1 = fmaf(iv.y, wreg[d + 1], p1);
        p0 = fmaf(iv.z, wreg[d + 2], p0);
        p1 = fmaf(iv.w, wreg[d + 3], p1);
        q0 = fmaf(yv.x, wreg[d + 0], q0);
        q1 = fmaf(yv.y, wreg[d + 1], q1);
        q0 = fmaf(yv.z, wreg[d + 2], q0);
        q1 = fmaf(yv.w, wreg[d + 3], q1);
    }
    const float z0 = wave_sum(fmaxf(p0 + p1 + bc1v, 0.f) * wc2v) + bc2v;
    const float z1 = wave_sum(fmaxf(q0 + q1 + bc1v, 0.f) * wc2v) + bc2v;
    const float zm = fmaxf(z0, z1);
    const float w0 = expf(z0 - zm), w1 = expf(z1 - zm);
    out[(size_t)idx * HD + lane] = fmaf(w0, indv, w1 * y8) / (w0 + w1);
}

extern "C" void kernel_launch(void* const* d_in, const int* in_sizes, int n_in,
                              void* d_out, int out_size, void* d_ws, size_t ws_size,
                              hipStream_t stream) {
    const float* x     = (const float*)d_in[0];
    const int*   Hm    = (const int*)  d_in[1];
    const int*   adj   = (const int*)  d_in[2];
    // d_in[3] = nhid (unused scalar)
    const float* W     = (const float*)d_in[4];
    const float* a_hyp = (const float*)d_in[5];
    const float* a_ind = (const float*)d_in[6];
    const float* Wc1   = (const float*)d_in[7];
    const float* bc1   = (const float*)d_in[8];
    const float* wc2   = (const float*)d_in[9];
    const float* bc2   = (const float*)d_in[10];
    float* out = (float*)d_out;

    float* ws       = (float*)d_ws;
    float* h        = ws;                                 // T*N*HD
    float* s_hyp    = h + (size_t)T_DIM * N_DIM * HD;     // T*N
    float* s_ind    = s_hyp + T_DIM * N_DIM;              // T*N
    float* m_e      = s_ind + T_DIM * N_DIM;              // T*E
    float* d_e      = m_e + T_DIM * E_DIM;                // T*E
    float* industry = d_e + T_DIM * E_DIM;                // T*N*HD

    k1_h_s<<<T_DIM * N_DIM / K1_R, 256, 0, stream>>>(x, W, a_hyp, a_ind, h, s_hyp, s_ind);
    k23_stats_industry<<<K2_BLOCKS + T_DIM * N_DIM / 4, 256, 0, stream>>>(
        Hm, adj, s_hyp, s_ind, h, m_e, d_e, industry);
    k4_final<<<T_DIM * N_DIM / 4, 256, 0, stream>>>(Hm, s_hyp, m_e, d_e, h, industry,
                                                    Wc1, bc1, wc2, bc2, out);
}